// Round 16
// baseline (215.588 us; speedup 1.0000x reference)
//
#include <hip/hip_runtime.h>
#include <hip/hip_bf16.h>

typedef unsigned short u16;
typedef unsigned int u32;
typedef __attribute__((ext_vector_type(8))) short bf16x8;   // 8 bf16 (4 VGPRs)
typedef __attribute__((ext_vector_type(4))) float f32x4;
typedef __attribute__((ext_vector_type(4))) u16 u16x4;

// hardware RNE cvt (compiler emits v_cvt_pk_bf16_f32 for adjacent pairs)
__device__ __forceinline__ u16 f2bf(float f) {
    __hip_bfloat16 h = __float2bfloat16(f);
    return *reinterpret_cast<u16*>(&h);
}
__device__ __forceinline__ float bf_lo(u32 u) {
    union { u32 u; float f; } v; v.u = u << 16; return v.f;
}
__device__ __forceinline__ float bf_hi(u32 u) {
    union { u32 u; float f; } v; v.u = u & 0xFFFF0000u; return v.f;
}
__device__ __forceinline__ u32 pack2(float a, float b) {
    return (u32)f2bf(a) | ((u32)f2bf(b) << 16);
}

#define NB2 256    // dst-range buckets
#define CHUNK 2048 // edges per routing block (8/thread; ~782 blocks -> good occupancy)

// ---------------- init: weights->bf16 transposed + bcur zero + sentinels ----------------
__global__ void init_kernel(const float* __restrict__ W1, u16* __restrict__ B1, int K1, int N1,
                            const float* __restrict__ W2, u16* __restrict__ B2, int K2, int N2,
                            int* __restrict__ bcur, u32* __restrict__ g1pad,
                            u32* __restrict__ g2pad, float* __restrict__ dinv, int N) {
    int i = blockIdx.x * 256 + threadIdx.x;
    int sz1 = K1 * N1;
    if (i < sz1) {
        int n = i / K1, k = i - n * K1;
        B1[i] = f2bf(W1[(size_t)k * N1 + n]);
    } else if (i - sz1 < K2 * N2) {
        int j = i - sz1;
        int n = j / K2, k = j - n * K2;
        B2[j] = f2bf(W2[(size_t)k * N2 + n]);
    }
    if (blockIdx.x == 0) {
        int t = threadIdx.x;
        bcur[t] = 0;                    // NB2 == 256 == blockDim
        if (t < 64) g1pad[t] = 0;       // sentinel row N of g1
        if (t < 32) g2pad[t] = 0;       // sentinel row N of g2
        if (t == 0) dinv[N] = 0.f;      // sentinel dinv (sentinel src = N)
    }
}

// ---------------- route body: edges -> 256 dst-range buckets (2KB of smem) ----------------
__device__ void route_body(int bid, char* smem, const int* __restrict__ src,
                           const int* __restrict__ dst, int E, int R2,
                           int* __restrict__ bcur, int2* __restrict__ bp, int bcap) {
    int* cnt = (int*)smem;
    int* cur = cnt + NB2;
    const int tid = threadIdx.x;
    const int base = bid * CHUNK;
    cnt[tid] = 0;
    __syncthreads();
#pragma unroll
    for (int i = 0; i < CHUNK / 256; i++) {
        int e = base + i * 256 + tid;
        if (e < E) atomicAdd(&cnt[dst[e] / R2], 1);
    }
    __syncthreads();
    {
        int c = cnt[tid];
        cur[tid] = c ? atomicAdd(&bcur[tid], c) : 0;
    }
    __syncthreads();
#pragma unroll
    for (int i = 0; i < CHUNK / 256; i++) {
        int e = base + i * 256 + tid;
        if (e < E) {
            int d = dst[e], s = src[e];
            int b = d / R2;
            int pos = atomicAdd(&cur[b], 1);
            if (pos < bcap) bp[(size_t)b * bcap + pos] = (int2){s, d};
        }
    }
}

// ---------------- gemm1 body: g1u = bf16(x @ W1t^T), NO dinv (20.5KB smem) ----------------
// LDS rows padded to 40 u16 (80B): frag reads 2 lanes/bank (free) instead of 8-way conflict.
__device__ void gemm1_body(int bid, char* smem, const float* __restrict__ A,
                           const u16* __restrict__ Bt, u16* __restrict__ G, int M) {
    constexpr int K = 256, BM = 128, BN = 128, BK = 32, BKP = 40, IFR = 4, JFR = 4, WM = 2;
    u16 (*As)[BKP] = (u16(*)[BKP])smem;
    u16 (*Bs)[BKP] = (u16(*)[BKP])(smem + BM * BKP * 2);
    const int tid = threadIdx.x;
    const int lane = tid & 63, wave = tid >> 6;
    const int r = lane & 15, g = lane >> 4;
    const int wm = wave % WM, wn = wave / WM;
    const int m0 = bid * BM;

    f32x4 acc[IFR][JFR];
#pragma unroll
    for (int i = 0; i < IFR; i++)
#pragma unroll
        for (int j = 0; j < JFR; j++) acc[i][j] = (f32x4){0.f, 0.f, 0.f, 0.f};

    for (int k0 = 0; k0 < K; k0 += BK) {
#pragma unroll
        for (int p = 0; p < 4; p++) {
            int q = tid + p * 256;
            int row = q >> 3, kq = (q & 7) << 2;
            int gr = m0 + row; if (gr >= M) gr = M - 1;   // clamp; stores guarded
            float4 a = *(const float4*)(A + (size_t)gr * K + k0 + kq);
            u16x4 v = { f2bf(a.x), f2bf(a.y), f2bf(a.z), f2bf(a.w) };
            *(u16x4*)&As[row][kq] = v;
        }
#pragma unroll
        for (int p = 0; p < BN / 32; p++) {
            int q = tid + p * 256;
            int row = q >> 3, kq = (q & 7) << 2;
            *(u16x4*)&Bs[row][kq] = *(const u16x4*)(Bt + (size_t)row * K + k0 + kq);
        }
        __syncthreads();

        bf16x8 af[IFR], bfr[JFR];
#pragma unroll
        for (int i = 0; i < IFR; i++)
            af[i] = *(const bf16x8*)&As[wm * (IFR * 16) + i * 16 + r][g * 8];
#pragma unroll
        for (int j = 0; j < JFR; j++)
            bfr[j] = *(const bf16x8*)&Bs[wn * (JFR * 16) + j * 16 + r][g * 8];
#pragma unroll
        for (int i = 0; i < IFR; i++)
#pragma unroll
            for (int j = 0; j < JFR; j++)
                acc[i][j] = __builtin_amdgcn_mfma_f32_16x16x32_bf16(af[i], bfr[j], acc[i][j], 0, 0, 0);
        __syncthreads();
    }

    // C/D layout: col=lane&15, row=(lane>>4)*4+reg
#pragma unroll
    for (int i = 0; i < IFR; i++) {
#pragma unroll
        for (int t = 0; t < 4; t++) {
            int row = m0 + wm * (IFR * 16) + i * 16 + g * 4 + t;
            if (row < M) {
#pragma unroll
                for (int j = 0; j < JFR; j++) {
                    int col = wn * (JFR * 16) + j * 16 + r;
                    G[(size_t)row * BN + col] = f2bf(acc[i][j][t]);
                }
            }
        }
    }
}

// ---------------- merged: route blocks co-scheduled with gemm1 blocks ----------------
__launch_bounds__(256)
__global__ void route_gemm1(const int* __restrict__ src, const int* __restrict__ dst, int E, int R2,
                            int* __restrict__ bcur, int2* __restrict__ bp, int bcap, int nroute,
                            const float* __restrict__ x, const u16* __restrict__ W1t,
                            u16* __restrict__ g1, int M, int ngemm) {
    __shared__ alignas(16) char smem[20480];
    int bid = blockIdx.x;
    int g = (nroute < ngemm) ? nroute : ngemm;
    if (bid < 2 * g) {
        if (bid & 1) route_body(bid >> 1, smem, src, dst, E, R2, bcur, bp, bcap);
        else         gemm1_body(bid >> 1, smem, x, W1t, g1, M);
    } else {
        int rm = bid - 2 * g;
        if (ngemm > nroute) gemm1_body(g + rm, smem, x, W1t, g1, M);
        else                route_body(g + rm, smem, src, dst, E, R2, bcur, bp, bcap);
    }
}

// ---------------- per-bucket CSR build, bucket pairs cached in LDS ----------------
__launch_bounds__(256)
__global__ void build_csr(const int2* __restrict__ bp2, const int* __restrict__ bcnt2, int bcap2,
                          int sreg, int R2, int N,
                          int* __restrict__ rs, int* __restrict__ re,
                          float* __restrict__ dinv, int* __restrict__ srcids) {
    __shared__ int2 pl[8300];        // bucket pair cache (bcap2 <= 8300), ~66KB
    __shared__ int bins[400];        // R2 <= 400
    __shared__ int tsum[256];
    const int b = blockIdx.x;
    const int tid = threadIdx.x;
    const int lo = b * R2;
    int hi = lo + R2; if (hi > N) hi = N;
    const int nb = hi - lo;
    if (nb <= 0) return;
    int cnt = bcnt2[b];
    if (cnt > bcap2) cnt = bcap2;
    const int2* mine = bp2 + (size_t)b * bcap2;

    for (int i = tid; i < nb; i += 256) bins[i] = 0;
    for (int i = tid; i < cnt; i += 256) pl[i] = mine[i];   // one global read of the bucket
    __syncthreads();
    for (int i = tid; i < cnt; i += 256) atomicAdd(&bins[pl[i].y - lo], 1);
    __syncthreads();

    const int base4 = tid * 4;
    int creal[4], cpad[4], ex[4];
    int run = 0;
#pragma unroll
    for (int k = 0; k < 4; k++) {
        int idx = base4 + k;
        creal[k] = 0; cpad[k] = 0; ex[k] = 0;
        if (idx < nb) {
            int c = bins[idx];
            creal[k] = c;
            cpad[k] = (c + 3) & ~3;
            dinv[lo + idx] = rsqrtf((float)c + 1.0f);
            ex[k] = run;
            run += cpad[k];
        }
    }
    tsum[tid] = run;
    __syncthreads();
    for (int off = 1; off < 256; off <<= 1) {
        int u = (tid >= off) ? tsum[tid - off] : 0;
        __syncthreads();
        tsum[tid] += u;
        __syncthreads();
    }
    const int toff = ((tid > 0) ? tsum[tid - 1] : 0) + b * sreg;
    __syncthreads();
#pragma unroll
    for (int k = 0; k < 4; k++) {
        int idx = base4 + k;
        if (idx < nb) {
            int st = toff + ex[k];
            bins[idx] = st;                    // absolute fill cursor
            rs[lo + idx] = st;
            re[lo + idx] = st + cpad[k];
            for (int q = creal[k]; q < cpad[k]; q++) srcids[st + q] = N;  // sentinel
        }
    }
    __syncthreads();
    for (int i = tid; i < cnt; i += 256) {
        int2 p = pl[i];
        int pos = atomicAdd(&bins[p.y - lo], 1);
        srcids[pos] = p.x;
    }
}

// ---------------- MFMA bf16 GEMM (gemm2): G = bf16((A @ Bt^T) * dinv[m]) ----------------
template <int K, int BN, int IFR, int JFR, int WM, int WN>
__launch_bounds__(256)
__global__ void gemm_mfma(const u16* __restrict__ A, const u16* __restrict__ Bt,
                          const float* __restrict__ dinv, u16* __restrict__ G, int M) {
    constexpr int BM = 128, BK = 32, BKP = 40;
    __shared__ u16 As[BM][BKP];
    __shared__ u16 Bs[BN][BKP];
    const int tid = threadIdx.x;
    const int lane = tid & 63, wave = tid >> 6;
    const int r = lane & 15, g = lane >> 4;
    const int wm = wave % WM, wn = wave / WM;
    const int m0 = blockIdx.x * BM;

    f32x4 acc[IFR][JFR];
#pragma unroll
    for (int i = 0; i < IFR; i++)
#pragma unroll
        for (int j = 0; j < JFR; j++) acc[i][j] = (f32x4){0.f, 0.f, 0.f, 0.f};

    for (int k0 = 0; k0 < K; k0 += BK) {
#pragma unroll
        for (int p = 0; p < 4; p++) {
            int q = tid + p * 256;
            int row = q >> 3, kq = (q & 7) << 2;
            int gr = m0 + row; if (gr >= M) gr = M - 1;   // clamp; stores guarded
            *(u16x4*)&As[row][kq] = *(const u16x4*)(A + (size_t)gr * K + k0 + kq);
        }
#pragma unroll
        for (int p = 0; p < BN / 32; p++) {
            int q = tid + p * 256;
            int row = q >> 3, kq = (q & 7) << 2;
            *(u16x4*)&Bs[row][kq] = *(const u16x4*)(Bt + (size_t)row * K + k0 + kq);
        }
        __syncthreads();

        bf16x8 af[IFR], bfr[JFR];
#pragma unroll
        for (int i = 0; i < IFR; i++)
            af[i] = *(const bf16x8*)&As[wm * (IFR * 16) + i * 16 + r][g * 8];
#pragma unroll
        for (int j = 0; j < JFR; j++)
            bfr[j] = *(const bf16x8*)&Bs[wn * (JFR * 16) + j * 16 + r][g * 8];
#pragma unroll
        for (int i = 0; i < IFR; i++)
#pragma unroll
            for (int j = 0; j < JFR; j++)
                acc[i][j] = __builtin_amdgcn_mfma_f32_16x16x32_bf16(af[i], bfr[j], acc[i][j], 0, 0, 0);
        __syncthreads();
    }

    // C/D layout: col=lane&15, row=(lane>>4)*4+reg
#pragma unroll
    for (int i = 0; i < IFR; i++) {
#pragma unroll
        for (int t = 0; t < 4; t++) {
            int row = m0 + wm * (IFR * 16) + i * 16 + g * 4 + t;
            if (row < M) {
                float dn = dinv[row];
#pragma unroll
                for (int j = 0; j < JFR; j++) {
                    int col = wn * (JFR * 16) + j * 16 + r;
                    G[(size_t)row * BN + col] = f2bf(acc[i][j][t] * dn);
                }
            }
        }
    }
}

// weighted accumulate: acc += v * wt (8 bf16 lanes). NOTE: param renamed 'wt' --
// a param named 'w' would be substituted into the member access v.w (macro hygiene!)
#define ACCW(v, wt) { a0 = fmaf(bf_lo(v.x), wt, a0); a1 = fmaf(bf_hi(v.x), wt, a1); \
                      a2 = fmaf(bf_lo(v.y), wt, a2); a3 = fmaf(bf_hi(v.y), wt, a3); \
                      a4 = fmaf(bf_lo(v.z), wt, a4); a5 = fmaf(bf_hi(v.z), wt, a5); \
                      a6 = fmaf(bf_lo(v.w), wt, a6); a7 = fmaf(bf_hi(v.w), wt, a7); }

// ---------------- agg F=128: quarter/node; per-src dinv weighting; pipelined int4 idx ----------------
__launch_bounds__(256)
__global__ void agg128(const uint4* __restrict__ g1, const float4* __restrict__ bias,
                       const int* __restrict__ rs, const int* __restrict__ re,
                       const int* __restrict__ srcids, const float* __restrict__ dinv,
                       uint4* __restrict__ h1, int n) {
    const int tq = threadIdx.x >> 4;       // quarter [0,16)
    const int c  = threadIdx.x & 15;       // 16B slice
    const int node = blockIdx.x * 16 + tq;
    if (node >= n) return;
    const float dn = dinv[node];
    uint4 sv = g1[(size_t)node * 16 + c];  // self (weight dn)
    float a0 = bf_lo(sv.x) * dn, a1 = bf_hi(sv.x) * dn, a2 = bf_lo(sv.y) * dn, a3 = bf_hi(sv.y) * dn;
    float a4 = bf_lo(sv.z) * dn, a5 = bf_hi(sv.z) * dn, a6 = bf_lo(sv.w) * dn, a7 = bf_hi(sv.w) * dn;

    int j = rs[node] >> 2;                 // int4-granular (segments 4-aligned+padded)
    const int jend = re[node] >> 2;
    const int4* ip = (const int4*)srcids;
    if (j < jend) {
        int4 idx = ip[j];
        for (++j; j < jend; ++j) {
            float w0 = dinv[idx.x], w1 = dinv[idx.y], w2 = dinv[idx.z], w3 = dinv[idx.w];
            uint4 v0 = g1[(size_t)idx.x * 16 + c];
            uint4 v1 = g1[(size_t)idx.y * 16 + c];
            uint4 v2 = g1[(size_t)idx.z * 16 + c];
            uint4 v3 = g1[(size_t)idx.w * 16 + c];
            int4 nxt = ip[j];              // prefetch next indices under the gathers
            ACCW(v0, w0); ACCW(v1, w1); ACCW(v2, w2); ACCW(v3, w3);
            idx = nxt;
        }
        float w0 = dinv[idx.x], w1 = dinv[idx.y], w2 = dinv[idx.z], w3 = dinv[idx.w];
        uint4 v0 = g1[(size_t)idx.x * 16 + c];
        uint4 v1 = g1[(size_t)idx.y * 16 + c];
        uint4 v2 = g1[(size_t)idx.z * 16 + c];
        uint4 v3 = g1[(size_t)idx.w * 16 + c];
        ACCW(v0, w0); ACCW(v1, w1); ACCW(v2, w2); ACCW(v3, w3);
    }

    float4 b0 = bias[c * 2], b1v = bias[c * 2 + 1];
    uint4 w;
    w.x = pack2(fmaxf(a0 * dn + b0.x, 0.f), fmaxf(a1 * dn + b0.y, 0.f));
    w.y = pack2(fmaxf(a2 * dn + b0.z, 0.f), fmaxf(a3 * dn + b0.w, 0.f));
    w.z = pack2(fmaxf(a4 * dn + b1v.x, 0.f), fmaxf(a5 * dn + b1v.y, 0.f));
    w.w = pack2(fmaxf(a6 * dn + b1v.z, 0.f), fmaxf(a7 * dn + b1v.w, 0.f));
    h1[(size_t)node * 16 + c] = w;
}

// ---------------- fused agg F=64 + head + log_softmax (g2 pre-scaled by gemm2) ----------------
__launch_bounds__(256)
__global__ void agg64out(const uint2* __restrict__ g2, const float4* __restrict__ bias,
                         const int* __restrict__ rs, const int* __restrict__ re,
                         const int* __restrict__ srcids, const float* __restrict__ dinv,
                         const float* __restrict__ Wo, const float* __restrict__ bo,
                         float* __restrict__ out, int n) {
    __shared__ float Ws[64 * 40];
    __shared__ float bs[40];
    __shared__ float h2s[16][68];          // row stride 68 -> quarters hit distinct banks
    for (int i = threadIdx.x; i < 64 * 40; i += 256) Ws[i] = Wo[i];
    if (threadIdx.x < 40) bs[threadIdx.x] = bo[threadIdx.x];

    const int tq = threadIdx.x >> 4;
    const int c  = threadIdx.x & 15;
    const int node = blockIdx.x * 16 + tq;
    if (node < n) {
        const float dn = dinv[node];
        uint2 sv = g2[(size_t)node * 16 + c];
        float a0 = bf_lo(sv.x), a1 = bf_hi(sv.x), a2 = bf_lo(sv.y), a3 = bf_hi(sv.y);
        int j = rs[node] >> 2;
        const int jend = re[node] >> 2;
        const int4* ip = (const int4*)srcids;
        if (j < jend) {
            int4 idx = ip[j];
            for (++j; j < jend; ++j) {
                uint2 v0 = g2[(size_t)idx.x * 16 + c];
                uint2 v1 = g2[(size_t)idx.y * 16 + c];
                uint2 v2 = g2[(size_t)idx.z * 16 + c];
                uint2 v3 = g2[(size_t)idx.w * 16 + c];
                int4 nxt = ip[j];
                a0 += (bf_lo(v0.x) + bf_lo(v1.x)) + (bf_lo(v2.x) + bf_lo(v3.x));
                a1 += (bf_hi(v0.x) + bf_hi(v1.x)) + (bf_hi(v2.x) + bf_hi(v3.x));
                a2 += (bf_lo(v0.y) + bf_lo(v1.y)) + (bf_lo(v2.y) + bf_lo(v3.y));
                a3 += (bf_hi(v0.y) + bf_hi(v1.y)) + (bf_hi(v2.y) + bf_hi(v3.y));
                idx = nxt;
            }
            uint2 v0 = g2[(size_t)idx.x * 16 + c];
            uint2 v1 = g2[(size_t)idx.y * 16 + c];
            uint2 v2 = g2[(size_t)idx.z * 16 + c];
            uint2 v3 = g2[(size_t)idx.w * 16 + c];
            a0 += (bf_lo(v0.x) + bf_lo(v1.x)) + (bf_lo(v2.x) + bf_lo(v3.x));
            a1 += (bf_hi(v0.x) + bf_hi(v1.x)) + (bf_hi(v2.x) + bf_hi(v3.x));
            a2 += (bf_lo(v0.y) + bf_lo(v1.y)) + (bf_lo(v2.y) + bf_lo(v3.y));
            a3 += (bf_hi(v0.y) + bf_hi(v1.y)) + (bf_hi(v2.y) + bf_hi(v3.y));
        }
        float4 bb = bias[c];
        float4 hv = { a0 * dn + bb.x, a1 * dn + bb.y, a2 * dn + bb.z, a3 * dn + bb.w };
        *(float4*)&h2s[tq][c * 4] = hv;
    }
    __syncthreads();

    if (node < n) {
        const int j2 = (c < 8) ? (c + 32) : 39;        // duplicate for c>=8, discarded
        float l0 = bs[c], l1 = bs[c + 16], l2 = bs[j2];
#pragma unroll 8
        for (int k = 0; k < 64; k++) {
            float hk = h2s[tq][k];
            l0 = fmaf(hk, Ws[k * 40 + c], l0);
            l1 = fmaf(hk, Ws[k * 40 + c + 16], l1);
            l2 = fmaf(hk, Ws[k * 40 + j2], l2);
        }
        float m = fmaxf(fmaxf(l0, l1), (c < 8) ? l2 : -3.0e38f);
#pragma unroll
        for (int o = 1; o < 16; o <<= 1) m = fmaxf(m, __shfl_xor(m, o));
        float s = expf(l0 - m) + expf(l1 - m) + ((c < 8) ? expf(l2 - m) : 0.f);
#pragma unroll
        for (int o = 1; o < 16; o <<= 1) s += __shfl_xor(s, o);
        float lse = m + logf(s);
        float* op = out + (size_t)node * 40;
        op[c] = l0 - lse;
        op[c + 16] = l1 - lse;
        if (c < 8) op[c + 32] = l2 - lse;
    }
}

extern "C" void kernel_launch(void* const* d_in, const int* in_sizes, int n_in,
                              void* d_out, int out_size, void* d_ws, size_t ws_size,
                              hipStream_t stream) {
    const float* x  = (const float*)d_in[0];
    const int*   ei = (const int*)d_in[1];
    const float* W1 = (const float*)d_in[2];
    const float* b1 = (const float*)d_in[3];
    const float* W2 = (const float*)d_in[4];
    const float* b2 = (const float*)d_in[5];
    const float* Wo = (const float*)d_in[6];
    const float* bo = (const float*)d_in[7];
    float* out = (float*)d_out;

    const int HID  = in_sizes[3];           // 128
    const int IN   = in_sizes[2] / HID;     // 256
    const int HID1 = in_sizes[5];           // 64
    const int N = in_sizes[0] / IN;         // 100000
    const int E = in_sizes[1] / 2;          // 1600000
    const int* src = ei;
    const int* dst = ei + E;

    const int R2 = (N + NB2 - 1) / NB2;     // 391
    const int bcap2 = E / NB2 + 2048;       // 8298 (<= 8300 LDS cache, ~26 sigma)
    const int sreg  = (bcap2 + 3 * R2 + 32 + 3) & ~3;   // region stride, %4==0 (alignment invariant)

    char* ws = (char*)d_ws;
    size_t off = 0;
    auto alloc = [&](size_t bytes) -> void* {
        void* p = ws + off;
        off += (bytes + 255) / 256 * 256;
        return p;
    };
    float* dinv   = (float*)alloc((size_t)(N + 1) * 4);    // +1: sentinel entry = 0
    int*   rs     = (int*)alloc((size_t)N * 4);
    int*   re     = (int*)alloc((size_t)N * 4);
    int*   bcur   = (int*)alloc(NB2 * 4);
    int*   srcids = (int*)alloc((size_t)NB2 * sreg * 4);   // ~9.7 MB
    u16*   W1t    = (u16*)alloc((size_t)IN * HID * 2);     // [128][256] bf16
    u16*   W2t    = (u16*)alloc((size_t)HID * HID1 * 2);   // [64][128] bf16
    // g1 and bp2 are now live SIMULTANEOUSLY (route ∥ gemm1) -> separate buffers
    int2*  bp2    = (int2*)alloc((size_t)NB2 * bcap2 * 8); // ~17 MB
    u16*   g1     = (u16*)alloc((size_t)(N + 1) * HID * 2);  // bf16 [N+1][128], unscaled
    u16*   h1     = (u16*)alloc((size_t)N * HID * 2);        // bf16 [N][128]
    u16*   g2     = (u16*)alloc((size_t)(N + 1) * HID1 * 2); // bf16 [N+1][64]

    // ---- init (weights cvt + bcur zero + sentinel rows + dinv sentinel) ----
    init_kernel<<<(IN * HID + HID * HID1 + 255) / 256, 256, 0, stream>>>(
        W1, W1t, IN, HID, W2, W2t, HID, HID1,
        bcur, (u32*)g1 + (size_t)N * 64, (u32*)g2 + (size_t)N * 32, dinv, N);

    // ---- merged: route (CSR bucketing) ∥ gemm1 (g1u = bf16(x @ W1)) ----
    const int nroute = (E + CHUNK - 1) / CHUNK;            // 782
    const int ngemm  = (N + 127) / 128;                    // 782
    route_gemm1<<<nroute + ngemm, 256, 0, stream>>>(
        src, dst, E, R2, bcur, bp2, bcap2, nroute, x, W1t, g1, N, ngemm);

    // ---- CSR finalize ----
    build_csr<<<NB2, 256, 0, stream>>>(bp2, bcur, bcap2, sreg, R2, N, rs, re, dinv, srcids);

    // layer 1 agg: h1 = bf16(relu(dinv[d]*(Σ dinv[s]*g1u[s] + dinv[d]*g1u[d]) + b1))
    agg128<<<(N + 15) / 16, 256, 0, stream>>>((const uint4*)g1, (const float4*)b1,
                                              rs, re, srcids, dinv, (uint4*)h1, N);

    // layer 2: g2 = bf16((h1 @ W2) * dinv); out = log_softmax((agg(g2)*dinv + b2) @ Wo + bo)
    gemm_mfma<128, 64, 2, 4, 4, 1><<<ngemm, 256, 0, stream>>>(h1, W2t, dinv, g2, N);
    agg64out<<<(N + 15) / 16, 256, 0, stream>>>((const uint2*)g2, (const float4*)b2,
                                                rs, re, srcids, dinv, Wo, bo, out, N);

    (void)ws_size; (void)n_in; (void)out_size; (void)HID1;
}

// Round 17
// 203.114 us; speedup vs baseline: 1.0614x; 1.0614x over previous
//
#include <hip/hip_runtime.h>
#include <hip/hip_bf16.h>

typedef unsigned short u16;
typedef unsigned int u32;
typedef __attribute__((ext_vector_type(8))) short bf16x8;   // 8 bf16 (4 VGPRs)
typedef __attribute__((ext_vector_type(4))) float f32x4;
typedef __attribute__((ext_vector_type(4))) u16 u16x4;

// hardware RNE cvt (compiler emits v_cvt_pk_bf16_f32 for adjacent pairs)
__device__ __forceinline__ u16 f2bf(float f) {
    __hip_bfloat16 h = __float2bfloat16(f);
    return *reinterpret_cast<u16*>(&h);
}
__device__ __forceinline__ float bf_lo(u32 u) {
    union { u32 u; float f; } v; v.u = u << 16; return v.f;
}
__device__ __forceinline__ float bf_hi(u32 u) {
    union { u32 u; float f; } v; v.u = u & 0xFFFF0000u; return v.f;
}
__device__ __forceinline__ u32 pack2(float a, float b) {
    return (u32)f2bf(a) | ((u32)f2bf(b) << 16);
}

#define NB2 256    // dst-range buckets
#define CHUNK 2048 // edges per routing block (8 per thread; 782 blocks -> ~12 waves/CU)

// ---------------- init: weights->bf16 transposed + bcur zero + sentinel rows ----------------
__global__ void init_kernel(const float* __restrict__ W1, u16* __restrict__ B1, int K1, int N1,
                            const float* __restrict__ W2, u16* __restrict__ B2, int K2, int N2,
                            int* __restrict__ bcur, u32* __restrict__ g1pad,
                            u32* __restrict__ g2pad) {
    int i = blockIdx.x * 256 + threadIdx.x;
    int sz1 = K1 * N1;
    if (i < sz1) {
        int n = i / K1, k = i - n * K1;
        B1[i] = f2bf(W1[(size_t)k * N1 + n]);
    } else if (i - sz1 < K2 * N2) {
        int j = i - sz1;
        int n = j / K2, k = j - n * K2;
        B2[j] = f2bf(W2[(size_t)k * N2 + n]);
    }
    if (blockIdx.x == 0) {
        int t = threadIdx.x;
        bcur[t] = 0;                    // NB2 == 256 == blockDim
        if (t < 64) g1pad[t] = 0;       // sentinel row N of g1 (beyond bp2's 17MB extent)
        if (t < 32) g2pad[t] = 0;       // sentinel row N of g2
    }
}

// ---------------- single-pass routing: edges -> 256 dst-range buckets ----------------
__launch_bounds__(256)
__global__ void route(const int* __restrict__ src, const int* __restrict__ dst, int E, int R2,
                      int* __restrict__ bcur, int2* __restrict__ bp, int bcap) {
    __shared__ int cnt[NB2];
    __shared__ int cur[NB2];
    const int tid = threadIdx.x;
    const int base = blockIdx.x * CHUNK;
    cnt[tid] = 0;
    __syncthreads();
#pragma unroll
    for (int i = 0; i < CHUNK / 256; i++) {
        int e = base + i * 256 + tid;
        if (e < E) atomicAdd(&cnt[dst[e] / R2], 1);
    }
    __syncthreads();
    {
        int c = cnt[tid];
        cur[tid] = c ? atomicAdd(&bcur[tid], c) : 0;
    }
    __syncthreads();
#pragma unroll
    for (int i = 0; i < CHUNK / 256; i++) {
        int e = base + i * 256 + tid;
        if (e < E) {
            int d = dst[e], s = src[e];
            int b = d / R2;
            int pos = atomicAdd(&cur[b], 1);
            if (pos < bcap) bp[(size_t)b * bcap + pos] = (int2){s, d};
        }
    }
}

// ---------------- per-bucket CSR build, bucket pairs cached in LDS ----------------
// rs/re per node; segments padded to x4 with sentinel src = N (zero row); fixed
// per-bucket srcids regions (b * sreg, sreg % 4 == 0: int4 alignment invariant)
__launch_bounds__(256)
__global__ void build_csr(const int2* __restrict__ bp2, const int* __restrict__ bcnt2, int bcap2,
                          int sreg, int R2, int N,
                          int* __restrict__ rs, int* __restrict__ re,
                          float* __restrict__ dinv, int* __restrict__ srcids) {
    __shared__ int2 pl[8300];        // bucket pair cache (bcap2 <= 8300), ~66KB
    __shared__ int bins[400];        // R2 <= 400
    __shared__ int tsum[256];
    const int b = blockIdx.x;
    const int tid = threadIdx.x;
    const int lo = b * R2;
    int hi = lo + R2; if (hi > N) hi = N;
    const int nb = hi - lo;
    if (nb <= 0) return;
    int cnt = bcnt2[b];
    if (cnt > bcap2) cnt = bcap2;
    const int2* mine = bp2 + (size_t)b * bcap2;

    for (int i = tid; i < nb; i += 256) bins[i] = 0;
    for (int i = tid; i < cnt; i += 256) pl[i] = mine[i];   // one global read of the bucket
    __syncthreads();
    for (int i = tid; i < cnt; i += 256) atomicAdd(&bins[pl[i].y - lo], 1);
    __syncthreads();

    const int base4 = tid * 4;
    int creal[4], cpad[4], ex[4];
    int run = 0;
#pragma unroll
    for (int k = 0; k < 4; k++) {
        int idx = base4 + k;
        creal[k] = 0; cpad[k] = 0; ex[k] = 0;
        if (idx < nb) {
            int c = bins[idx];
            creal[k] = c;
            cpad[k] = (c + 3) & ~3;
            dinv[lo + idx] = rsqrtf((float)c + 1.0f);
            ex[k] = run;
            run += cpad[k];
        }
    }
    tsum[tid] = run;
    __syncthreads();
    for (int off = 1; off < 256; off <<= 1) {
        int u = (tid >= off) ? tsum[tid - off] : 0;
        __syncthreads();
        tsum[tid] += u;
        __syncthreads();
    }
    const int toff = ((tid > 0) ? tsum[tid - 1] : 0) + b * sreg;
    __syncthreads();
#pragma unroll
    for (int k = 0; k < 4; k++) {
        int idx = base4 + k;
        if (idx < nb) {
            int st = toff + ex[k];
            bins[idx] = st;                    // absolute fill cursor
            rs[lo + idx] = st;
            re[lo + idx] = st + cpad[k];
            for (int q = creal[k]; q < cpad[k]; q++) srcids[st + q] = N;  // sentinel
        }
    }
    __syncthreads();
    for (int i = tid; i < cnt; i += 256) {
        int2 p = pl[i];
        int pos = atomicAdd(&bins[p.y - lo], 1);
        srcids[pos] = p.x;
    }
}

// ---------------- MFMA bf16 GEMM: G[m][n] = bf16( (A @ Bt^T)[m][n] * dinv[m] ) ----------------
// LDS rows padded to 40 u16 (80 B): frag reads land 2 lanes/bank (free) instead of 8-way.
template <int K, int BN, int IFR, int JFR, int WM, int WN, bool ABF16>
__launch_bounds__(256)
__global__ void gemm_mfma(const void* __restrict__ Av, const u16* __restrict__ Bt,
                          const float* __restrict__ dinv, u16* __restrict__ G, int M) {
    constexpr int BM = 128, BK = 32, BKP = 40;
    __shared__ u16 As[BM][BKP];
    __shared__ u16 Bs[BN][BKP];
    const int tid = threadIdx.x;
    const int lane = tid & 63, wave = tid >> 6;
    const int r = lane & 15, g = lane >> 4;
    const int wm = wave % WM, wn = wave / WM;
    const int m0 = blockIdx.x * BM;

    f32x4 acc[IFR][JFR];
#pragma unroll
    for (int i = 0; i < IFR; i++)
#pragma unroll
        for (int j = 0; j < JFR; j++) acc[i][j] = (f32x4){0.f, 0.f, 0.f, 0.f};

    for (int k0 = 0; k0 < K; k0 += BK) {
#pragma unroll
        for (int p = 0; p < 4; p++) {
            int q = tid + p * 256;
            int row = q >> 3, kq = (q & 7) << 2;
            int gr = m0 + row; if (gr >= M) gr = M - 1;   // clamp; stores guarded
            if constexpr (ABF16) {
                const u16* A = (const u16*)Av;
                *(u16x4*)&As[row][kq] = *(const u16x4*)(A + (size_t)gr * K + k0 + kq);
            } else {
                const float* A = (const float*)Av;
                float4 a = *(const float4*)(A + (size_t)gr * K + k0 + kq);
                u16x4 v = { f2bf(a.x), f2bf(a.y), f2bf(a.z), f2bf(a.w) };
                *(u16x4*)&As[row][kq] = v;
            }
        }
#pragma unroll
        for (int p = 0; p < BN / 32; p++) {
            int q = tid + p * 256;
            int row = q >> 3, kq = (q & 7) << 2;
            *(u16x4*)&Bs[row][kq] = *(const u16x4*)(Bt + (size_t)row * K + k0 + kq);
        }
        __syncthreads();

        bf16x8 af[IFR], bfr[JFR];
#pragma unroll
        for (int i = 0; i < IFR; i++)
            af[i] = *(const bf16x8*)&As[wm * (IFR * 16) + i * 16 + r][g * 8];
#pragma unroll
        for (int j = 0; j < JFR; j++)
            bfr[j] = *(const bf16x8*)&Bs[wn * (JFR * 16) + j * 16 + r][g * 8];
#pragma unroll
        for (int i = 0; i < IFR; i++)
#pragma unroll
            for (int j = 0; j < JFR; j++)
                acc[i][j] = __builtin_amdgcn_mfma_f32_16x16x32_bf16(af[i], bfr[j], acc[i][j], 0, 0, 0);
        __syncthreads();
    }

    // C/D layout: col=lane&15, row=(lane>>4)*4+reg
#pragma unroll
    for (int i = 0; i < IFR; i++) {
#pragma unroll
        for (int t = 0; t < 4; t++) {
            int row = m0 + wm * (IFR * 16) + i * 16 + g * 4 + t;
            if (row < M) {
                float dn = dinv[row];
#pragma unroll
                for (int j = 0; j < JFR; j++) {
                    int col = wn * (JFR * 16) + j * 16 + r;
                    G[(size_t)row * BN + col] = f2bf(acc[i][j][t] * dn);
                }
            }
        }
    }
}

#define ACC8(v) { a0 += bf_lo(v.x); a1 += bf_hi(v.x); a2 += bf_lo(v.y); a3 += bf_hi(v.y); \
                  a4 += bf_lo(v.z); a5 += bf_hi(v.z); a6 += bf_lo(v.w); a7 += bf_hi(v.w); }

// ---------------- agg F=128: 16-lane quarter per node; pipelined int4 index loads ----------------
__launch_bounds__(256)
__global__ void agg128(const uint4* __restrict__ g1, const float4* __restrict__ bias,
                       const int* __restrict__ rs, const int* __restrict__ re,
                       const int* __restrict__ srcids, const float* __restrict__ dinv,
                       uint4* __restrict__ h1, int n) {
    const int tq = threadIdx.x >> 4;       // quarter [0,16)
    const int c  = threadIdx.x & 15;       // 16B slice
    const int node = blockIdx.x * 16 + tq;
    if (node >= n) return;
    const float dn = dinv[node];
    uint4 sv = g1[(size_t)node * 16 + c];
    float a0 = bf_lo(sv.x), a1 = bf_hi(sv.x), a2 = bf_lo(sv.y), a3 = bf_hi(sv.y);
    float a4 = bf_lo(sv.z), a5 = bf_hi(sv.z), a6 = bf_lo(sv.w), a7 = bf_hi(sv.w);

    int j = rs[node] >> 2;                 // int4-granular (segments 4-aligned+padded)
    const int jend = re[node] >> 2;
    const int4* ip = (const int4*)srcids;
    if (j < jend) {
        int4 idx = ip[j];
        for (++j; j < jend; ++j) {
            uint4 v0 = g1[(size_t)idx.x * 16 + c];
            uint4 v1 = g1[(size_t)idx.y * 16 + c];
            uint4 v2 = g1[(size_t)idx.z * 16 + c];
            uint4 v3 = g1[(size_t)idx.w * 16 + c];
            int4 nxt = ip[j];              // prefetch next indices under the gathers
            ACC8(v0); ACC8(v1); ACC8(v2); ACC8(v3);
            idx = nxt;
        }
        uint4 v0 = g1[(size_t)idx.x * 16 + c];
        uint4 v1 = g1[(size_t)idx.y * 16 + c];
        uint4 v2 = g1[(size_t)idx.z * 16 + c];
        uint4 v3 = g1[(size_t)idx.w * 16 + c];
        ACC8(v0); ACC8(v1); ACC8(v2); ACC8(v3);
    }

    float4 b0 = bias[c * 2], b1v = bias[c * 2 + 1];
    uint4 w;
    w.x = pack2(fmaxf(a0 * dn + b0.x, 0.f), fmaxf(a1 * dn + b0.y, 0.f));
    w.y = pack2(fmaxf(a2 * dn + b0.z, 0.f), fmaxf(a3 * dn + b0.w, 0.f));
    w.z = pack2(fmaxf(a4 * dn + b1v.x, 0.f), fmaxf(a5 * dn + b1v.y, 0.f));
    w.w = pack2(fmaxf(a6 * dn + b1v.z, 0.f), fmaxf(a7 * dn + b1v.w, 0.f));
    h1[(size_t)node * 16 + c] = w;
}

// ---------------- fused agg F=64 + head + log_softmax ----------------
__launch_bounds__(256)
__global__ void agg64out(const uint2* __restrict__ g2, const float4* __restrict__ bias,
                         const int* __restrict__ rs, const int* __restrict__ re,
                         const int* __restrict__ srcids, const float* __restrict__ dinv,
                         const float* __restrict__ Wo, const float* __restrict__ bo,
                         float* __restrict__ out, int n) {
    __shared__ float Ws[64 * 40];
    __shared__ float bs[40];
    __shared__ float h2s[16][68];          // row stride 68 -> quarters hit distinct banks
    for (int i = threadIdx.x; i < 64 * 40; i += 256) Ws[i] = Wo[i];
    if (threadIdx.x < 40) bs[threadIdx.x] = bo[threadIdx.x];

    const int tq = threadIdx.x >> 4;
    const int c  = threadIdx.x & 15;
    const int node = blockIdx.x * 16 + tq;
    if (node < n) {
        const float dn = dinv[node];
        uint2 sv = g2[(size_t)node * 16 + c];
        float a0 = bf_lo(sv.x), a1 = bf_hi(sv.x), a2 = bf_lo(sv.y), a3 = bf_hi(sv.y);
        int j = rs[node] >> 2;
        const int jend = re[node] >> 2;
        const int4* ip = (const int4*)srcids;
        if (j < jend) {
            int4 idx = ip[j];
            for (++j; j < jend; ++j) {
                uint2 v0 = g2[(size_t)idx.x * 16 + c];
                uint2 v1 = g2[(size_t)idx.y * 16 + c];
                uint2 v2 = g2[(size_t)idx.z * 16 + c];
                uint2 v3 = g2[(size_t)idx.w * 16 + c];
                int4 nxt = ip[j];
                a0 += (bf_lo(v0.x) + bf_lo(v1.x)) + (bf_lo(v2.x) + bf_lo(v3.x));
                a1 += (bf_hi(v0.x) + bf_hi(v1.x)) + (bf_hi(v2.x) + bf_hi(v3.x));
                a2 += (bf_lo(v0.y) + bf_lo(v1.y)) + (bf_lo(v2.y) + bf_lo(v3.y));
                a3 += (bf_hi(v0.y) + bf_hi(v1.y)) + (bf_hi(v2.y) + bf_hi(v3.y));
                idx = nxt;
            }
            uint2 v0 = g2[(size_t)idx.x * 16 + c];
            uint2 v1 = g2[(size_t)idx.y * 16 + c];
            uint2 v2 = g2[(size_t)idx.z * 16 + c];
            uint2 v3 = g2[(size_t)idx.w * 16 + c];
            a0 += (bf_lo(v0.x) + bf_lo(v1.x)) + (bf_lo(v2.x) + bf_lo(v3.x));
            a1 += (bf_hi(v0.x) + bf_hi(v1.x)) + (bf_hi(v2.x) + bf_hi(v3.x));
            a2 += (bf_lo(v0.y) + bf_lo(v1.y)) + (bf_lo(v2.y) + bf_lo(v3.y));
            a3 += (bf_hi(v0.y) + bf_hi(v1.y)) + (bf_hi(v2.y) + bf_hi(v3.y));
        }
        float4 bb = bias[c];
        float4 hv = { a0 * dn + bb.x, a1 * dn + bb.y, a2 * dn + bb.z, a3 * dn + bb.w };
        *(float4*)&h2s[tq][c * 4] = hv;
    }
    __syncthreads();

    if (node < n) {
        const int j2 = (c < 8) ? (c + 32) : 39;        // duplicate for c>=8, discarded
        float l0 = bs[c], l1 = bs[c + 16], l2 = bs[j2];
#pragma unroll 8
        for (int k = 0; k < 64; k++) {
            float hk = h2s[tq][k];
            l0 = fmaf(hk, Ws[k * 40 + c], l0);
            l1 = fmaf(hk, Ws[k * 40 + c + 16], l1);
            l2 = fmaf(hk, Ws[k * 40 + j2], l2);
        }
        float m = fmaxf(fmaxf(l0, l1), (c < 8) ? l2 : -3.0e38f);
#pragma unroll
        for (int o = 1; o < 16; o <<= 1) m = fmaxf(m, __shfl_xor(m, o));
        float s = expf(l0 - m) + expf(l1 - m) + ((c < 8) ? expf(l2 - m) : 0.f);
#pragma unroll
        for (int o = 1; o < 16; o <<= 1) s += __shfl_xor(s, o);
        float lse = m + logf(s);
        float* op = out + (size_t)node * 40;
        op[c] = l0 - lse;
        op[c + 16] = l1 - lse;
        if (c < 8) op[c + 32] = l2 - lse;
    }
}

extern "C" void kernel_launch(void* const* d_in, const int* in_sizes, int n_in,
                              void* d_out, int out_size, void* d_ws, size_t ws_size,
                              hipStream_t stream) {
    const float* x  = (const float*)d_in[0];
    const int*   ei = (const int*)d_in[1];
    const float* W1 = (const float*)d_in[2];
    const float* b1 = (const float*)d_in[3];
    const float* W2 = (const float*)d_in[4];
    const float* b2 = (const float*)d_in[5];
    const float* Wo = (const float*)d_in[6];
    const float* bo = (const float*)d_in[7];
    float* out = (float*)d_out;

    const int HID  = in_sizes[3];           // 128
    const int IN   = in_sizes[2] / HID;     // 256
    const int HID1 = in_sizes[5];           // 64
    const int N = in_sizes[0] / IN;         // 100000
    const int E = in_sizes[1] / 2;          // 1600000
    const int* src = ei;
    const int* dst = ei + E;

    const int R2 = (N + NB2 - 1) / NB2;     // 391
    const int bcap2 = E / NB2 + 2048;       // 8298 (<= 8300 LDS cache, ~26 sigma)
    const int sreg  = (bcap2 + 3 * R2 + 32 + 3) & ~3;   // region stride, %4==0 (alignment invariant)

    char* ws = (char*)d_ws;
    size_t off = 0;
    auto alloc = [&](size_t bytes) -> void* {
        void* p = ws + off;
        off += (bytes + 255) / 256 * 256;
        return p;
    };
    float* dinv   = (float*)alloc((size_t)N * 4);
    int*   rs     = (int*)alloc((size_t)N * 4);
    int*   re     = (int*)alloc((size_t)N * 4);
    int*   bcur   = (int*)alloc(NB2 * 4);
    int*   srcids = (int*)alloc((size_t)NB2 * sreg * 4);   // ~9.7 MB
    u16*   W1t    = (u16*)alloc((size_t)IN * HID * 2);     // [128][256] bf16
    u16*   W2t    = (u16*)alloc((size_t)HID * HID1 * 2);   // [64][128] bf16
    // shared region: bp2 (CSR build, 17MB) -> g1 (gemm1/agg128, 25.6MB); sequential.
    // g1's sentinel row N sits at byte 25.6e6 > bp2's 17e6 extent -> init can zero it early.
    size_t bp2Bytes = (size_t)NB2 * bcap2 * 8;
    size_t gBytes = (size_t)(N + 1) * HID * 2;
    size_t sharedBytes = (gBytes > bp2Bytes) ? gBytes : bp2Bytes;
    char*  shared = (char*)alloc(sharedBytes);
    int2*  bp2    = (int2*)shared;
    u16*   g1     = (u16*)shared;                          // bf16 [N+1][128]
    u16*   h1     = (u16*)alloc((size_t)N * HID * 2);      // bf16 [N][128]
    u16*   g2     = (u16*)alloc((size_t)(N + 1) * HID1 * 2); // bf16 [N+1][64]

    // ---- init (weights cvt + bcur zero + sentinel rows) ----
    init_kernel<<<(IN * HID + HID * HID1 + 255) / 256, 256, 0, stream>>>(
        W1, W1t, IN, HID, W2, W2t, HID, HID1,
        bcur, (u32*)g1 + (size_t)N * 64, (u32*)g2 + (size_t)N * 32);

    // ---- CSR build: single-pass 256-way routing, padded rows ----
    const int nchunk = (E + CHUNK - 1) / CHUNK;            // 782
    route<<<nchunk, 256, 0, stream>>>(src, dst, E, R2, bcur, bp2, bcap2);
    build_csr<<<NB2, 256, 0, stream>>>(bp2, bcur, bcap2, sreg, R2, N, rs, re, dinv, srcids);

    const int gblocks = (N + 127) / 128;
    // layer 1: g1 = bf16((x @ W1) * dinv); h1 = bf16(relu(agg(g1)*dinv + b1))
    gemm_mfma<256, 128, 4, 4, 2, 2, false><<<gblocks, 256, 0, stream>>>(x, W1t, dinv, g1, N);
    agg128<<<(N + 15) / 16, 256, 0, stream>>>((const uint4*)g1, (const float4*)b1,
                                              rs, re, srcids, dinv, (uint4*)h1, N);

    // layer 2: g2 = bf16((h1 @ W2) * dinv); out = log_softmax((agg(g2)*dinv + b2) @ Wo + bo)
    gemm_mfma<128, 64, 2, 4, 4, 1, true><<<gblocks, 256, 0, stream>>>(h1, W2t, dinv, g2, N);
    agg64out<<<(N + 15) / 16, 256, 0, stream>>>((const uint2*)g2, (const float4*)b2,
                                                rs, re, srcids, dinv, Wo, bo, out, N);

    (void)ws_size; (void)n_in; (void)out_size; (void)HID1;
}

// Round 18
// 196.615 us; speedup vs baseline: 1.0965x; 1.0331x over previous
//
#include <hip/hip_runtime.h>
#include <hip/hip_bf16.h>

typedef unsigned short u16;
typedef unsigned int u32;
typedef __attribute__((ext_vector_type(8))) short bf16x8;   // 8 bf16 (4 VGPRs)
typedef __attribute__((ext_vector_type(4))) float f32x4;
typedef __attribute__((ext_vector_type(4))) u16 u16x4;

// hardware RNE cvt (compiler emits v_cvt_pk_bf16_f32 for adjacent pairs)
__device__ __forceinline__ u16 f2bf(float f) {
    __hip_bfloat16 h = __float2bfloat16(f);
    return *reinterpret_cast<u16*>(&h);
}
__device__ __forceinline__ float bf_lo(u32 u) {
    union { u32 u; float f; } v; v.u = u << 16; return v.f;
}
__device__ __forceinline__ float bf_hi(u32 u) {
    union { u32 u; float f; } v; v.u = u & 0xFFFF0000u; return v.f;
}
__device__ __forceinline__ u32 pack2(float a, float b) {
    return (u32)f2bf(a) | ((u32)f2bf(b) << 16);
}

#define NB2 256    // dst-range buckets
#define CHUNK 2048 // edges per routing block (8 per thread; 782 blocks -> ~12 waves/CU)

// ---------------- init: weights->bf16 transposed + bcur zero + sentinel rows ----------------
__global__ void init_kernel(const float* __restrict__ W1, u16* __restrict__ B1, int K1, int N1,
                            const float* __restrict__ W2, u16* __restrict__ B2, int K2, int N2,
                            int* __restrict__ bcur, u32* __restrict__ g1pad,
                            u32* __restrict__ g2pad) {
    int i = blockIdx.x * 256 + threadIdx.x;
    int sz1 = K1 * N1;
    if (i < sz1) {
        int n = i / K1, k = i - n * K1;
        B1[i] = f2bf(W1[(size_t)k * N1 + n]);
    } else if (i - sz1 < K2 * N2) {
        int j = i - sz1;
        int n = j / K2, k = j - n * K2;
        B2[j] = f2bf(W2[(size_t)k * N2 + n]);
    }
    if (blockIdx.x == 0) {
        int t = threadIdx.x;
        bcur[t] = 0;                    // NB2 == 256 == blockDim
        if (t < 64) g1pad[t] = 0;       // sentinel row N of g1 (beyond bp2's 17MB extent)
        if (t < 32) g2pad[t] = 0;       // sentinel row N of g2
    }
}

// ---------------- single-pass routing: edges -> 256 dst-range buckets ----------------
__launch_bounds__(256)
__global__ void route(const int* __restrict__ src, const int* __restrict__ dst, int E, int R2,
                      int* __restrict__ bcur, int2* __restrict__ bp, int bcap) {
    __shared__ int cnt[NB2];
    __shared__ int cur[NB2];
    const int tid = threadIdx.x;
    const int base = blockIdx.x * CHUNK;
    cnt[tid] = 0;
    __syncthreads();
#pragma unroll
    for (int i = 0; i < CHUNK / 256; i++) {
        int e = base + i * 256 + tid;
        if (e < E) atomicAdd(&cnt[dst[e] / R2], 1);
    }
    __syncthreads();
    {
        int c = cnt[tid];
        cur[tid] = c ? atomicAdd(&bcur[tid], c) : 0;
    }
    __syncthreads();
#pragma unroll
    for (int i = 0; i < CHUNK / 256; i++) {
        int e = base + i * 256 + tid;
        if (e < E) {
            int d = dst[e], s = src[e];
            int b = d / R2;
            int pos = atomicAdd(&cur[b], 1);
            if (pos < bcap) bp[(size_t)b * bcap + pos] = (int2){s, d};
        }
    }
}

// ---------------- per-bucket CSR build, bucket pairs cached in LDS ----------------
__launch_bounds__(256)
__global__ void build_csr(const int2* __restrict__ bp2, const int* __restrict__ bcnt2, int bcap2,
                          int sreg, int R2, int N,
                          int* __restrict__ rs, int* __restrict__ re,
                          float* __restrict__ dinv, int* __restrict__ srcids) {
    __shared__ int2 pl[8300];        // bucket pair cache (bcap2 <= 8300), ~66KB
    __shared__ int bins[400];        // R2 <= 400
    __shared__ int tsum[256];
    const int b = blockIdx.x;
    const int tid = threadIdx.x;
    const int lo = b * R2;
    int hi = lo + R2; if (hi > N) hi = N;
    const int nb = hi - lo;
    if (nb <= 0) return;
    int cnt = bcnt2[b];
    if (cnt > bcap2) cnt = bcap2;
    const int2* mine = bp2 + (size_t)b * bcap2;

    for (int i = tid; i < nb; i += 256) bins[i] = 0;
    for (int i = tid; i < cnt; i += 256) pl[i] = mine[i];   // one global read of the bucket
    __syncthreads();
    for (int i = tid; i < cnt; i += 256) atomicAdd(&bins[pl[i].y - lo], 1);
    __syncthreads();

    const int base4 = tid * 4;
    int creal[4], cpad[4], ex[4];
    int run = 0;
#pragma unroll
    for (int k = 0; k < 4; k++) {
        int idx = base4 + k;
        creal[k] = 0; cpad[k] = 0; ex[k] = 0;
        if (idx < nb) {
            int c = bins[idx];
            creal[k] = c;
            cpad[k] = (c + 3) & ~3;
            dinv[lo + idx] = rsqrtf((float)c + 1.0f);
            ex[k] = run;
            run += cpad[k];
        }
    }
    tsum[tid] = run;
    __syncthreads();
    for (int off = 1; off < 256; off <<= 1) {
        int u = (tid >= off) ? tsum[tid - off] : 0;
        __syncthreads();
        tsum[tid] += u;
        __syncthreads();
    }
    const int toff = ((tid > 0) ? tsum[tid - 1] : 0) + b * sreg;
    __syncthreads();
#pragma unroll
    for (int k = 0; k < 4; k++) {
        int idx = base4 + k;
        if (idx < nb) {
            int st = toff + ex[k];
            bins[idx] = st;                    // absolute fill cursor
            rs[lo + idx] = st;
            re[lo + idx] = st + cpad[k];
            for (int q = creal[k]; q < cpad[k]; q++) srcids[st + q] = N;  // sentinel
        }
    }
    __syncthreads();
    for (int i = tid; i < cnt; i += 256) {
        int2 p = pl[i];
        int pos = atomicAdd(&bins[p.y - lo], 1);
        srcids[pos] = p.x;
    }
}

// ---------------- MFMA bf16 GEMM: G[m][n] = bf16( (A @ Bt^T)[m][n] * dinv[m] ) ----------------
// BM=64 -> 1563 blocks (~6/CU): latency-bound barrier drains overlap across blocks.
// LDS rows padded to 40 u16 (80 B): frag reads land 2 lanes/bank (free) instead of 8-way.
template <int BM, int K, int BN, int IFR, int JFR, int WM, int WN, bool ABF16>
__launch_bounds__(256)
__global__ void gemm_mfma(const void* __restrict__ Av, const u16* __restrict__ Bt,
                          const float* __restrict__ dinv, u16* __restrict__ G, int M) {
    constexpr int BK = 32, BKP = 40;
    __shared__ u16 As[BM][BKP];
    __shared__ u16 Bs[BN][BKP];
    const int tid = threadIdx.x;
    const int lane = tid & 63, wave = tid >> 6;
    const int r = lane & 15, g = lane >> 4;
    const int wm = wave % WM, wn = wave / WM;
    const int m0 = blockIdx.x * BM;

    f32x4 acc[IFR][JFR];
#pragma unroll
    for (int i = 0; i < IFR; i++)
#pragma unroll
        for (int j = 0; j < JFR; j++) acc[i][j] = (f32x4){0.f, 0.f, 0.f, 0.f};

    for (int k0 = 0; k0 < K; k0 += BK) {
#pragma unroll
        for (int p = 0; p < BM / 32; p++) {
            int q = tid + p * 256;
            int row = q >> 3, kq = (q & 7) << 2;
            int gr = m0 + row; if (gr >= M) gr = M - 1;   // clamp; stores guarded
            if constexpr (ABF16) {
                const u16* A = (const u16*)Av;
                *(u16x4*)&As[row][kq] = *(const u16x4*)(A + (size_t)gr * K + k0 + kq);
            } else {
                const float* A = (const float*)Av;
                float4 a = *(const float4*)(A + (size_t)gr * K + k0 + kq);
                u16x4 v = { f2bf(a.x), f2bf(a.y), f2bf(a.z), f2bf(a.w) };
                *(u16x4*)&As[row][kq] = v;
            }
        }
#pragma unroll
        for (int p = 0; p < BN / 32; p++) {
            int q = tid + p * 256;
            int row = q >> 3, kq = (q & 7) << 2;
            *(u16x4*)&Bs[row][kq] = *(const u16x4*)(Bt + (size_t)row * K + k0 + kq);
        }
        __syncthreads();

        bf16x8 af[IFR], bfr[JFR];
#pragma unroll
        for (int i = 0; i < IFR; i++)
            af[i] = *(const bf16x8*)&As[wm * (IFR * 16) + i * 16 + r][g * 8];
#pragma unroll
        for (int j = 0; j < JFR; j++)
            bfr[j] = *(const bf16x8*)&Bs[wn * (JFR * 16) + j * 16 + r][g * 8];
#pragma unroll
        for (int i = 0; i < IFR; i++)
#pragma unroll
            for (int j = 0; j < JFR; j++)
                acc[i][j] = __builtin_amdgcn_mfma_f32_16x16x32_bf16(af[i], bfr[j], acc[i][j], 0, 0, 0);
        __syncthreads();
    }

    // C/D layout: col=lane&15, row=(lane>>4)*4+reg
#pragma unroll
    for (int i = 0; i < IFR; i++) {
#pragma unroll
        for (int t = 0; t < 4; t++) {
            int row = m0 + wm * (IFR * 16) + i * 16 + g * 4 + t;
            if (row < M) {
                float dn = dinv[row];
#pragma unroll
                for (int j = 0; j < JFR; j++) {
                    int col = wn * (JFR * 16) + j * 16 + r;
                    G[(size_t)row * BN + col] = f2bf(acc[i][j][t] * dn);
                }
            }
        }
    }
}

#define ACC8(v) { a0 += bf_lo(v.x); a1 += bf_hi(v.x); a2 += bf_lo(v.y); a3 += bf_hi(v.y); \
                  a4 += bf_lo(v.z); a5 += bf_hi(v.z); a6 += bf_lo(v.w); a7 += bf_hi(v.w); }

// ---------------- agg F=128: 16-lane quarter per node; pipelined int4 index loads ----------------
__launch_bounds__(256)
__global__ void agg128(const uint4* __restrict__ g1, const float4* __restrict__ bias,
                       const int* __restrict__ rs, const int* __restrict__ re,
                       const int* __restrict__ srcids, const float* __restrict__ dinv,
                       uint4* __restrict__ h1, int n) {
    const int tq = threadIdx.x >> 4;       // quarter [0,16)
    const int c  = threadIdx.x & 15;       // 16B slice
    const int node = blockIdx.x * 16 + tq;
    if (node >= n) return;
    const float dn = dinv[node];
    uint4 sv = g1[(size_t)node * 16 + c];
    float a0 = bf_lo(sv.x), a1 = bf_hi(sv.x), a2 = bf_lo(sv.y), a3 = bf_hi(sv.y);
    float a4 = bf_lo(sv.z), a5 = bf_hi(sv.z), a6 = bf_lo(sv.w), a7 = bf_hi(sv.w);

    int j = rs[node] >> 2;                 // int4-granular (segments 4-aligned+padded)
    const int jend = re[node] >> 2;
    const int4* ip = (const int4*)srcids;
    if (j < jend) {
        int4 idx = ip[j];
        for (++j; j < jend; ++j) {
            uint4 v0 = g1[(size_t)idx.x * 16 + c];
            uint4 v1 = g1[(size_t)idx.y * 16 + c];
            uint4 v2 = g1[(size_t)idx.z * 16 + c];
            uint4 v3 = g1[(size_t)idx.w * 16 + c];
            int4 nxt = ip[j];              // prefetch next indices under the gathers
            ACC8(v0); ACC8(v1); ACC8(v2); ACC8(v3);
            idx = nxt;
        }
        uint4 v0 = g1[(size_t)idx.x * 16 + c];
        uint4 v1 = g1[(size_t)idx.y * 16 + c];
        uint4 v2 = g1[(size_t)idx.z * 16 + c];
        uint4 v3 = g1[(size_t)idx.w * 16 + c];
        ACC8(v0); ACC8(v1); ACC8(v2); ACC8(v3);
    }

    float4 b0 = bias[c * 2], b1v = bias[c * 2 + 1];
    uint4 w;
    w.x = pack2(fmaxf(a0 * dn + b0.x, 0.f), fmaxf(a1 * dn + b0.y, 0.f));
    w.y = pack2(fmaxf(a2 * dn + b0.z, 0.f), fmaxf(a3 * dn + b0.w, 0.f));
    w.z = pack2(fmaxf(a4 * dn + b1v.x, 0.f), fmaxf(a5 * dn + b1v.y, 0.f));
    w.w = pack2(fmaxf(a6 * dn + b1v.z, 0.f), fmaxf(a7 * dn + b1v.w, 0.f));
    h1[(size_t)node * 16 + c] = w;
}

// ---------------- fused agg F=64 + head + log_softmax ----------------
__launch_bounds__(256)
__global__ void agg64out(const uint2* __restrict__ g2, const float4* __restrict__ bias,
                         const int* __restrict__ rs, const int* __restrict__ re,
                         const int* __restrict__ srcids, const float* __restrict__ dinv,
                         const float* __restrict__ Wo, const float* __restrict__ bo,
                         float* __restrict__ out, int n) {
    __shared__ float Ws[64 * 40];
    __shared__ float bs[40];
    __shared__ float h2s[16][68];          // row stride 68 -> quarters hit distinct banks
    for (int i = threadIdx.x; i < 64 * 40; i += 256) Ws[i] = Wo[i];
    if (threadIdx.x < 40) bs[threadIdx.x] = bo[threadIdx.x];

    const int tq = threadIdx.x >> 4;
    const int c  = threadIdx.x & 15;
    const int node = blockIdx.x * 16 + tq;
    if (node < n) {
        const float dn = dinv[node];
        uint2 sv = g2[(size_t)node * 16 + c];
        float a0 = bf_lo(sv.x), a1 = bf_hi(sv.x), a2 = bf_lo(sv.y), a3 = bf_hi(sv.y);
        int j = rs[node] >> 2;
        const int jend = re[node] >> 2;
        const int4* ip = (const int4*)srcids;
        if (j < jend) {
            int4 idx = ip[j];
            for (++j; j < jend; ++j) {
                uint2 v0 = g2[(size_t)idx.x * 16 + c];
                uint2 v1 = g2[(size_t)idx.y * 16 + c];
                uint2 v2 = g2[(size_t)idx.z * 16 + c];
                uint2 v3 = g2[(size_t)idx.w * 16 + c];
                int4 nxt = ip[j];
                a0 += (bf_lo(v0.x) + bf_lo(v1.x)) + (bf_lo(v2.x) + bf_lo(v3.x));
                a1 += (bf_hi(v0.x) + bf_hi(v1.x)) + (bf_hi(v2.x) + bf_hi(v3.x));
                a2 += (bf_lo(v0.y) + bf_lo(v1.y)) + (bf_lo(v2.y) + bf_lo(v3.y));
                a3 += (bf_hi(v0.y) + bf_hi(v1.y)) + (bf_hi(v2.y) + bf_hi(v3.y));
                idx = nxt;
            }
            uint2 v0 = g2[(size_t)idx.x * 16 + c];
            uint2 v1 = g2[(size_t)idx.y * 16 + c];
            uint2 v2 = g2[(size_t)idx.z * 16 + c];
            uint2 v3 = g2[(size_t)idx.w * 16 + c];
            a0 += (bf_lo(v0.x) + bf_lo(v1.x)) + (bf_lo(v2.x) + bf_lo(v3.x));
            a1 += (bf_hi(v0.x) + bf_hi(v1.x)) + (bf_hi(v2.x) + bf_hi(v3.x));
            a2 += (bf_lo(v0.y) + bf_lo(v1.y)) + (bf_lo(v2.y) + bf_lo(v3.y));
            a3 += (bf_hi(v0.y) + bf_hi(v1.y)) + (bf_hi(v2.y) + bf_hi(v3.y));
        }
        float4 bb = bias[c];
        float4 hv = { a0 * dn + bb.x, a1 * dn + bb.y, a2 * dn + bb.z, a3 * dn + bb.w };
        *(float4*)&h2s[tq][c * 4] = hv;
    }
    __syncthreads();

    if (node < n) {
        const int j2 = (c < 8) ? (c + 32) : 39;        // duplicate for c>=8, discarded
        float l0 = bs[c], l1 = bs[c + 16], l2 = bs[j2];
#pragma unroll 8
        for (int k = 0; k < 64; k++) {
            float hk = h2s[tq][k];
            l0 = fmaf(hk, Ws[k * 40 + c], l0);
            l1 = fmaf(hk, Ws[k * 40 + c + 16], l1);
            l2 = fmaf(hk, Ws[k * 40 + j2], l2);
        }
        float m = fmaxf(fmaxf(l0, l1), (c < 8) ? l2 : -3.0e38f);
#pragma unroll
        for (int o = 1; o < 16; o <<= 1) m = fmaxf(m, __shfl_xor(m, o));
        float s = expf(l0 - m) + expf(l1 - m) + ((c < 8) ? expf(l2 - m) : 0.f);
#pragma unroll
        for (int o = 1; o < 16; o <<= 1) s += __shfl_xor(s, o);
        float lse = m + logf(s);
        float* op = out + (size_t)node * 40;
        op[c] = l0 - lse;
        op[c + 16] = l1 - lse;
        if (c < 8) op[c + 32] = l2 - lse;
    }
}

extern "C" void kernel_launch(void* const* d_in, const int* in_sizes, int n_in,
                              void* d_out, int out_size, void* d_ws, size_t ws_size,
                              hipStream_t stream) {
    const float* x  = (const float*)d_in[0];
    const int*   ei = (const int*)d_in[1];
    const float* W1 = (const float*)d_in[2];
    const float* b1 = (const float*)d_in[3];
    const float* W2 = (const float*)d_in[4];
    const float* b2 = (const float*)d_in[5];
    const float* Wo = (const float*)d_in[6];
    const float* bo = (const float*)d_in[7];
    float* out = (float*)d_out;

    const int HID  = in_sizes[3];           // 128
    const int IN   = in_sizes[2] / HID;     // 256
    const int HID1 = in_sizes[5];           // 64
    const int N = in_sizes[0] / IN;         // 100000
    const int E = in_sizes[1] / 2;          // 1600000
    const int* src = ei;
    const int* dst = ei + E;

    const int R2 = (N + NB2 - 1) / NB2;     // 391
    const int bcap2 = E / NB2 + 2048;       // 8298 (<= 8300 LDS cache, ~26 sigma)
    const int sreg  = (bcap2 + 3 * R2 + 32 + 3) & ~3;   // region stride, %4==0 (alignment invariant)

    char* ws = (char*)d_ws;
    size_t off = 0;
    auto alloc = [&](size_t bytes) -> void* {
        void* p = ws + off;
        off += (bytes + 255) / 256 * 256;
        return p;
    };
    float* dinv   = (float*)alloc((size_t)N * 4);
    int*   rs     = (int*)alloc((size_t)N * 4);
    int*   re     = (int*)alloc((size_t)N * 4);
    int*   bcur   = (int*)alloc(NB2 * 4);
    int*   srcids = (int*)alloc((size_t)NB2 * sreg * 4);   // ~9.7 MB
    u16*   W1t    = (u16*)alloc((size_t)IN * HID * 2);     // [128][256] bf16
    u16*   W2t    = (u16*)alloc((size_t)HID * HID1 * 2);   // [64][128] bf16
    // shared region: bp2 (CSR build, 17MB) -> g1 (gemm1/agg128, 25.6MB); sequential.
    size_t bp2Bytes = (size_t)NB2 * bcap2 * 8;
    size_t gBytes = (size_t)(N + 1) * HID * 2;
    size_t sharedBytes = (gBytes > bp2Bytes) ? gBytes : bp2Bytes;
    char*  shared = (char*)alloc(sharedBytes);
    int2*  bp2    = (int2*)shared;
    u16*   g1     = (u16*)shared;                          // bf16 [N+1][128]
    u16*   h1     = (u16*)alloc((size_t)N * HID * 2);      // bf16 [N][128]
    u16*   g2     = (u16*)alloc((size_t)(N + 1) * HID1 * 2); // bf16 [N+1][64]

    // ---- init (weights cvt + bcur zero + sentinel rows) ----
    init_kernel<<<(IN * HID + HID * HID1 + 255) / 256, 256, 0, stream>>>(
        W1, W1t, IN, HID, W2, W2t, HID, HID1,
        bcur, (u32*)g1 + (size_t)N * 64, (u32*)g2 + (size_t)N * 32);

    // ---- CSR build: single-pass 256-way routing, padded rows ----
    const int nchunk = (E + CHUNK - 1) / CHUNK;            // 782
    route<<<nchunk, 256, 0, stream>>>(src, dst, E, R2, bcur, bp2, bcap2);
    build_csr<<<NB2, 256, 0, stream>>>(bp2, bcur, bcap2, sreg, R2, N, rs, re, dinv, srcids);

    const int gblocks = (N + 63) / 64;                     // 1563 (~6 blocks/CU)
    // layer 1: g1 = bf16((x @ W1) * dinv); h1 = bf16(relu(agg(g1)*dinv + b1))
    gemm_mfma<64, 256, 128, 2, 4, 2, 2, false><<<gblocks, 256, 0, stream>>>(x, W1t, dinv, g1, N);
    agg128<<<(N + 15) / 16, 256, 0, stream>>>((const uint4*)g1, (const float4*)b1,
                                              rs, re, srcids, dinv, (uint4*)h1, N);

    // layer 2: g2 = bf16((h1 @ W2) * dinv); out = log_softmax((agg(g2)*dinv + b2) @ Wo + bo)
    gemm_mfma<64, 128, 64, 1, 4, 4, 1, true><<<gblocks, 256, 0, stream>>>(h1, W2t, dinv, g2, N);
    agg64out<<<(N + 15) / 16, 256, 0, stream>>>((const uint2*)g2, (const float4*)b2,
                                                rs, re, srcids, dinv, Wo, bo, out, N);

    (void)ws_size; (void)n_in; (void)out_size; (void)HID1;
}

// Round 20
// 189.309 us; speedup vs baseline: 1.1388x; 1.0386x over previous
//
#include <hip/hip_runtime.h>
#include <hip/hip_bf16.h>

typedef unsigned short u16;
typedef unsigned int u32;
typedef __attribute__((ext_vector_type(8))) short bf16x8;   // 8 bf16 (4 VGPRs)
typedef __attribute__((ext_vector_type(4))) float f32x4;
typedef __attribute__((ext_vector_type(4))) u16 u16x4;

// hardware RNE cvt (compiler emits v_cvt_pk_bf16_f32 for adjacent pairs)
__device__ __forceinline__ u16 f2bf(float f) {
    __hip_bfloat16 h = __float2bfloat16(f);
    return *reinterpret_cast<u16*>(&h);
}
__device__ __forceinline__ float bf_lo(u32 u) {
    union { u32 u; float f; } v; v.u = u << 16; return v.f;
}
__device__ __forceinline__ float bf_hi(u32 u) {
    union { u32 u; float f; } v; v.u = u & 0xFFFF0000u; return v.f;
}
__device__ __forceinline__ u32 pack2(float a, float b) {
    return (u32)f2bf(a) | ((u32)f2bf(b) << 16);
}

#define NB2 256    // dst-range buckets
#define CHUNK 2048 // edges per routing block (8 per thread; 782 blocks -> ~12 waves/CU)

// ---------------- init: weights->bf16 transposed + bcur zero + sentinel rows ----------------
__global__ void init_kernel(const float* __restrict__ W1, u16* __restrict__ B1, int K1, int N1,
                            const float* __restrict__ W2, u16* __restrict__ B2, int K2, int N2,
                            int* __restrict__ bcur, u32* __restrict__ g1pad,
                            u32* __restrict__ g2pad) {
    int i = blockIdx.x * 256 + threadIdx.x;
    int sz1 = K1 * N1;
    if (i < sz1) {
        int n = i / K1, k = i - n * K1;
        B1[i] = f2bf(W1[(size_t)k * N1 + n]);
    } else if (i - sz1 < K2 * N2) {
        int j = i - sz1;
        int n = j / K2, k = j - n * K2;
        B2[j] = f2bf(W2[(size_t)k * N2 + n]);
    }
    if (blockIdx.x == 0) {
        int t = threadIdx.x;
        bcur[t] = 0;                    // NB2 == 256 == blockDim
        if (t < 64) g1pad[t] = 0;       // sentinel row N of g1 (beyond bp2's 17MB extent)
        if (t < 32) g2pad[t] = 0;       // sentinel row N of g2
    }
}

// ---------------- single-pass routing: edges -> 256 dst-range buckets ----------------
__launch_bounds__(256)
__global__ void route(const int* __restrict__ src, const int* __restrict__ dst, int E, int R2,
                      int* __restrict__ bcur, int2* __restrict__ bp, int bcap) {
    __shared__ int cnt[NB2];
    __shared__ int cur[NB2];
    const int tid = threadIdx.x;
    const int base = blockIdx.x * CHUNK;
    cnt[tid] = 0;
    __syncthreads();
#pragma unroll
    for (int i = 0; i < CHUNK / 256; i++) {
        int e = base + i * 256 + tid;
        if (e < E) atomicAdd(&cnt[dst[e] / R2], 1);
    }
    __syncthreads();
    {
        int c = cnt[tid];
        cur[tid] = c ? atomicAdd(&bcur[tid], c) : 0;
    }
    __syncthreads();
#pragma unroll
    for (int i = 0; i < CHUNK / 256; i++) {
        int e = base + i * 256 + tid;
        if (e < E) {
            int d = dst[e], s = src[e];
            int b = d / R2;
            int pos = atomicAdd(&cur[b], 1);
            if (pos < bcap) bp[(size_t)b * bcap + pos] = (int2){s, d};
        }
    }
}

// ---------------- per-bucket CSR build, bucket pairs cached in LDS ----------------
__launch_bounds__(256)
__global__ void build_csr(const int2* __restrict__ bp2, const int* __restrict__ bcnt2, int bcap2,
                          int sreg, int R2, int N,
                          int* __restrict__ rs, int* __restrict__ re,
                          float* __restrict__ dinv, int* __restrict__ srcids) {
    __shared__ int2 pl[8300];        // bucket pair cache (bcap2 <= 8300), ~66KB
    __shared__ int bins[400];        // R2 <= 400
    __shared__ int tsum[256];
    const int b = blockIdx.x;
    const int tid = threadIdx.x;
    const int lo = b * R2;
    int hi = lo + R2; if (hi > N) hi = N;
    const int nb = hi - lo;
    if (nb <= 0) return;
    int cnt = bcnt2[b];
    if (cnt > bcap2) cnt = bcap2;
    const int2* mine = bp2 + (size_t)b * bcap2;

    for (int i = tid; i < nb; i += 256) bins[i] = 0;
    for (int i = tid; i < cnt; i += 256) pl[i] = mine[i];   // one global read of the bucket
    __syncthreads();
    for (int i = tid; i < cnt; i += 256) atomicAdd(&bins[pl[i].y - lo], 1);
    __syncthreads();

    const int base4 = tid * 4;
    int creal[4], cpad[4], ex[4];
    int run = 0;
#pragma unroll
    for (int k = 0; k < 4; k++) {
        int idx = base4 + k;
        creal[k] = 0; cpad[k] = 0; ex[k] = 0;
        if (idx < nb) {
            int c = bins[idx];
            creal[k] = c;
            cpad[k] = (c + 3) & ~3;
            dinv[lo + idx] = rsqrtf((float)c + 1.0f);
            ex[k] = run;
            run += cpad[k];
        }
    }
    tsum[tid] = run;
    __syncthreads();
    for (int off = 1; off < 256; off <<= 1) {
        int u = (tid >= off) ? tsum[tid - off] : 0;
        __syncthreads();
        tsum[tid] += u;
        __syncthreads();
    }
    const int toff = ((tid > 0) ? tsum[tid - 1] : 0) + b * sreg;
    __syncthreads();
#pragma unroll
    for (int k = 0; k < 4; k++) {
        int idx = base4 + k;
        if (idx < nb) {
            int st = toff + ex[k];
            bins[idx] = st;                    // absolute fill cursor
            rs[lo + idx] = st;
            re[lo + idx] = st + cpad[k];
            for (int q = creal[k]; q < cpad[k]; q++) srcids[st + q] = N;  // sentinel
        }
    }
    __syncthreads();
    for (int i = tid; i < cnt; i += 256) {
        int2 p = pl[i];
        int pos = atomicAdd(&bins[p.y - lo], 1);
        srcids[pos] = p.x;
    }
}

// ---------------- MFMA bf16 GEMM (gemm1): G = bf16((A @ Bt^T) * dinv[m]) ----------------
// BM=64 -> 1563 blocks (~6/CU). LDS rows padded to 40 u16 (80B): 2 lanes/bank frag reads.
template <int BM, int K, int BN, int IFR, int JFR, int WM, int WN, bool ABF16>
__launch_bounds__(256)
__global__ void gemm_mfma(const void* __restrict__ Av, const u16* __restrict__ Bt,
                          const float* __restrict__ dinv, u16* __restrict__ G, int M) {
    constexpr int BK = 32, BKP = 40;
    __shared__ u16 As[BM][BKP];
    __shared__ u16 Bs[BN][BKP];
    const int tid = threadIdx.x;
    const int lane = tid & 63, wave = tid >> 6;
    const int r = lane & 15, g = lane >> 4;
    const int wm = wave % WM, wn = wave / WM;
    const int m0 = blockIdx.x * BM;

    f32x4 acc[IFR][JFR];
#pragma unroll
    for (int i = 0; i < IFR; i++)
#pragma unroll
        for (int j = 0; j < JFR; j++) acc[i][j] = (f32x4){0.f, 0.f, 0.f, 0.f};

    for (int k0 = 0; k0 < K; k0 += BK) {
#pragma unroll
        for (int p = 0; p < BM / 32; p++) {
            int q = tid + p * 256;
            int row = q >> 3, kq = (q & 7) << 2;
            int gr = m0 + row; if (gr >= M) gr = M - 1;   // clamp; stores guarded
            if constexpr (ABF16) {
                const u16* A = (const u16*)Av;
                *(u16x4*)&As[row][kq] = *(const u16x4*)(A + (size_t)gr * K + k0 + kq);
            } else {
                const float* A = (const float*)Av;
                float4 a = *(const float4*)(A + (size_t)gr * K + k0 + kq);
                u16x4 v = { f2bf(a.x), f2bf(a.y), f2bf(a.z), f2bf(a.w) };
                *(u16x4*)&As[row][kq] = v;
            }
        }
#pragma unroll
        for (int p = 0; p < BN / 32; p++) {
            int q = tid + p * 256;
            int row = q >> 3, kq = (q & 7) << 2;
            *(u16x4*)&Bs[row][kq] = *(const u16x4*)(Bt + (size_t)row * K + k0 + kq);
        }
        __syncthreads();

        bf16x8 af[IFR], bfr[JFR];
#pragma unroll
        for (int i = 0; i < IFR; i++)
            af[i] = *(const bf16x8*)&As[wm * (IFR * 16) + i * 16 + r][g * 8];
#pragma unroll
        for (int j = 0; j < JFR; j++)
            bfr[j] = *(const bf16x8*)&Bs[wn * (JFR * 16) + j * 16 + r][g * 8];
#pragma unroll
        for (int i = 0; i < IFR; i++)
#pragma unroll
            for (int j = 0; j < JFR; j++)
                acc[i][j] = __builtin_amdgcn_mfma_f32_16x16x32_bf16(af[i], bfr[j], acc[i][j], 0, 0, 0);
        __syncthreads();
    }

    // C/D layout: col=lane&15, row=(lane>>4)*4+reg
#pragma unroll
    for (int i = 0; i < IFR; i++) {
#pragma unroll
        for (int t = 0; t < 4; t++) {
            int row = m0 + wm * (IFR * 16) + i * 16 + g * 4 + t;
            if (row < M) {
                float dn = dinv[row];
#pragma unroll
                for (int j = 0; j < JFR; j++) {
                    int col = wn * (JFR * 16) + j * 16 + r;
                    G[(size_t)row * BN + col] = f2bf(acc[i][j][t] * dn);
                }
            }
        }
    }
}

#define ACC8(v) { a0 += bf_lo(v.x); a1 += bf_hi(v.x); a2 += bf_lo(v.y); a3 += bf_hi(v.y); \
                  a4 += bf_lo(v.z); a5 += bf_hi(v.z); a6 += bf_lo(v.w); a7 += bf_hi(v.w); }

// ---------------- fused agg F=128 + gemm2: g2 = bf16((relu(agg(g1)+b1) @ W2) * dinv) ----------
// Gather identical to round-18 agg128. The block's 16 h1 rows (128 bf16 = 64 u32 each!)
// are staged in LDS hq[16][68] (64 data u32 + 4 pad; 272B row stride = 16B-aligned,
// 272 mod 128 = 16 -> frag reads 2 lanes/bank). Each wave then computes one 16-col
// n-tile of h1 @ W2 with 4 MFMAs (B-frags preloaded from L2-hot W2t).
__launch_bounds__(256)
__global__ void agg128g2(const uint4* __restrict__ g1, const float4* __restrict__ bias,
                         const int* __restrict__ rs, const int* __restrict__ re,
                         const int* __restrict__ srcids, const float* __restrict__ dinv,
                         const u16* __restrict__ W2t, u16* __restrict__ g2, int n) {
    __shared__ u32 hq[16][68];             // 16 nodes x 64 k-pairs (+4 pad)
    const int tid = threadIdx.x;
    const int lane = tid & 63, wv = tid >> 6;
    const int tq = tid >> 4;               // quarter = node within block [0,16)
    const int c  = tid & 15;               // 16B slice

    // preload B-fragments for this wave's n-tile (cols 16*wv .. +16), K=128 in 4 steps
    bf16x8 bfrag[4];
    {
        int col = wv * 16 + (lane & 15);
        int koff = (lane >> 4) * 8;
#pragma unroll
        for (int s = 0; s < 4; s++)
            bfrag[s] = *(const bf16x8*)(W2t + (size_t)col * 128 + s * 32 + koff);
    }

    const int node = blockIdx.x * 16 + tq;
    uint4 w = {0u, 0u, 0u, 0u};
    if (node < n) {
        const float dn = dinv[node];
        uint4 sv = g1[(size_t)node * 16 + c];
        float a0 = bf_lo(sv.x), a1 = bf_hi(sv.x), a2 = bf_lo(sv.y), a3 = bf_hi(sv.y);
        float a4 = bf_lo(sv.z), a5 = bf_hi(sv.z), a6 = bf_lo(sv.w), a7 = bf_hi(sv.w);

        int j = rs[node] >> 2;             // int4-granular (segments 4-aligned+padded)
        const int jend = re[node] >> 2;
        const int4* ip = (const int4*)srcids;
        if (j < jend) {
            int4 idx = ip[j];
            for (++j; j < jend; ++j) {
                uint4 v0 = g1[(size_t)idx.x * 16 + c];
                uint4 v1 = g1[(size_t)idx.y * 16 + c];
                uint4 v2 = g1[(size_t)idx.z * 16 + c];
                uint4 v3 = g1[(size_t)idx.w * 16 + c];
                int4 nxt = ip[j];          // prefetch next indices under the gathers
                ACC8(v0); ACC8(v1); ACC8(v2); ACC8(v3);
                idx = nxt;
            }
            uint4 v0 = g1[(size_t)idx.x * 16 + c];
            uint4 v1 = g1[(size_t)idx.y * 16 + c];
            uint4 v2 = g1[(size_t)idx.z * 16 + c];
            uint4 v3 = g1[(size_t)idx.w * 16 + c];
            ACC8(v0); ACC8(v1); ACC8(v2); ACC8(v3);
        }

        float4 b0 = bias[c * 2], b1v = bias[c * 2 + 1];
        w.x = pack2(fmaxf(a0 * dn + b0.x, 0.f), fmaxf(a1 * dn + b0.y, 0.f));
        w.y = pack2(fmaxf(a2 * dn + b0.z, 0.f), fmaxf(a3 * dn + b0.w, 0.f));
        w.z = pack2(fmaxf(a4 * dn + b1v.x, 0.f), fmaxf(a5 * dn + b1v.y, 0.f));
        w.w = pack2(fmaxf(a6 * dn + b1v.z, 0.f), fmaxf(a7 * dn + b1v.w, 0.f));
    }
    *(uint4*)&hq[tq][c * 4] = w;           // h1 row slice: u32 indices c*4 .. c*4+3 of 64
    __syncthreads();

    // per-wave 16x16 n-tile of h1 @ W2 (A rows = 16 nodes, K = 128)
    const int r = lane & 15, g = lane >> 4;
    f32x4 acc = (f32x4){0.f, 0.f, 0.f, 0.f};
#pragma unroll
    for (int s = 0; s < 4; s++) {
        // node r, k = 32s + 8g .. +8  ->  u32 pair index 16s + 4g .. +4
        bf16x8 af = *(const bf16x8*)&hq[r][s * 16 + g * 4];
        acc = __builtin_amdgcn_mfma_f32_16x16x32_bf16(af, bfrag[s], acc, 0, 0, 0);
    }
    // C/D: col = lane&15 (within n-tile), row = (lane>>4)*4 + reg (node within block)
#pragma unroll
    for (int t = 0; t < 4; t++) {
        int m = g * 4 + t;
        int nd = blockIdx.x * 16 + m;
        if (nd < n) {
            float dn = dinv[nd];
            g2[(size_t)nd * 64 + wv * 16 + r] = f2bf(acc[t] * dn);
        }
    }
}

// ---------------- fused agg F=64 + head + log_softmax ----------------
__launch_bounds__(256)
__global__ void agg64out(const uint2* __restrict__ g2, const float4* __restrict__ bias,
                         const int* __restrict__ rs, const int* __restrict__ re,
                         const int* __restrict__ srcids, const float* __restrict__ dinv,
                         const float* __restrict__ Wo, const float* __restrict__ bo,
                         float* __restrict__ out, int n) {
    __shared__ float Ws[64 * 40];
    __shared__ float bs[40];
    __shared__ float h2s[16][68];          // row stride 68 -> quarters hit distinct banks
    for (int i = threadIdx.x; i < 64 * 40; i += 256) Ws[i] = Wo[i];
    if (threadIdx.x < 40) bs[threadIdx.x] = bo[threadIdx.x];

    const int tq = threadIdx.x >> 4;
    const int c  = threadIdx.x & 15;
    const int node = blockIdx.x * 16 + tq;
    if (node < n) {
        const float dn = dinv[node];
        uint2 sv = g2[(size_t)node * 16 + c];
        float a0 = bf_lo(sv.x), a1 = bf_hi(sv.x), a2 = bf_lo(sv.y), a3 = bf_hi(sv.y);
        int j = rs[node] >> 2;
        const int jend = re[node] >> 2;
        const int4* ip = (const int4*)srcids;
        if (j < jend) {
            int4 idx = ip[j];
            for (++j; j < jend; ++j) {
                uint2 v0 = g2[(size_t)idx.x * 16 + c];
                uint2 v1 = g2[(size_t)idx.y * 16 + c];
                uint2 v2 = g2[(size_t)idx.z * 16 + c];
                uint2 v3 = g2[(size_t)idx.w * 16 + c];
                int4 nxt = ip[j];
                a0 += (bf_lo(v0.x) + bf_lo(v1.x)) + (bf_lo(v2.x) + bf_lo(v3.x));
                a1 += (bf_hi(v0.x) + bf_hi(v1.x)) + (bf_hi(v2.x) + bf_hi(v3.x));
                a2 += (bf_lo(v0.y) + bf_lo(v1.y)) + (bf_lo(v2.y) + bf_lo(v3.y));
                a3 += (bf_hi(v0.y) + bf_hi(v1.y)) + (bf_hi(v2.y) + bf_hi(v3.y));
                idx = nxt;
            }
            uint2 v0 = g2[(size_t)idx.x * 16 + c];
            uint2 v1 = g2[(size_t)idx.y * 16 + c];
            uint2 v2 = g2[(size_t)idx.z * 16 + c];
            uint2 v3 = g2[(size_t)idx.w * 16 + c];
            a0 += (bf_lo(v0.x) + bf_lo(v1.x)) + (bf_lo(v2.x) + bf_lo(v3.x));
            a1 += (bf_hi(v0.x) + bf_hi(v1.x)) + (bf_hi(v2.x) + bf_hi(v3.x));
            a2 += (bf_lo(v0.y) + bf_lo(v1.y)) + (bf_lo(v2.y) + bf_lo(v3.y));
            a3 += (bf_hi(v0.y) + bf_hi(v1.y)) + (bf_hi(v2.y) + bf_hi(v3.y));
        }
        float4 bb = bias[c];
        float4 hv = { a0 * dn + bb.x, a1 * dn + bb.y, a2 * dn + bb.z, a3 * dn + bb.w };
        *(float4*)&h2s[tq][c * 4] = hv;
    }
    __syncthreads();

    if (node < n) {
        const int j2 = (c < 8) ? (c + 32) : 39;        // duplicate for c>=8, discarded
        float l0 = bs[c], l1 = bs[c + 16], l2 = bs[j2];
#pragma unroll 8
        for (int k = 0; k < 64; k++) {
            float hk = h2s[tq][k];
            l0 = fmaf(hk, Ws[k * 40 + c], l0);
            l1 = fmaf(hk, Ws[k * 40 + c + 16], l1);
            l2 = fmaf(hk, Ws[k * 40 + j2], l2);
        }
        float m = fmaxf(fmaxf(l0, l1), (c < 8) ? l2 : -3.0e38f);
#pragma unroll
        for (int o = 1; o < 16; o <<= 1) m = fmaxf(m, __shfl_xor(m, o));
        float s = expf(l0 - m) + expf(l1 - m) + ((c < 8) ? expf(l2 - m) : 0.f);
#pragma unroll
        for (int o = 1; o < 16; o <<= 1) s += __shfl_xor(s, o);
        float lse = m + logf(s);
        float* op = out + (size_t)node * 40;
        op[c] = l0 - lse;
        op[c + 16] = l1 - lse;
        if (c < 8) op[c + 32] = l2 - lse;
    }
}

extern "C" void kernel_launch(void* const* d_in, const int* in_sizes, int n_in,
                              void* d_out, int out_size, void* d_ws, size_t ws_size,
                              hipStream_t stream) {
    const float* x  = (const float*)d_in[0];
    const int*   ei = (const int*)d_in[1];
    const float* W1 = (const float*)d_in[2];
    const float* b1 = (const float*)d_in[3];
    const float* W2 = (const float*)d_in[4];
    const float* b2 = (const float*)d_in[5];
    const float* Wo = (const float*)d_in[6];
    const float* bo = (const float*)d_in[7];
    float* out = (float*)d_out;

    const int HID  = in_sizes[3];           // 128
    const int IN   = in_sizes[2] / HID;     // 256
    const int HID1 = in_sizes[5];           // 64
    const int N = in_sizes[0] / IN;         // 100000
    const int E = in_sizes[1] / 2;          // 1600000
    const int* src = ei;
    const int* dst = ei + E;

    const int R2 = (N + NB2 - 1) / NB2;     // 391
    const int bcap2 = E / NB2 + 2048;       // 8298 (<= 8300 LDS cache, ~26 sigma)
    const int sreg  = (bcap2 + 3 * R2 + 32 + 3) & ~3;   // region stride, %4==0 (alignment invariant)

    char* ws = (char*)d_ws;
    size_t off = 0;
    auto alloc = [&](size_t bytes) -> void* {
        void* p = ws + off;
        off += (bytes + 255) / 256 * 256;
        return p;
    };
    float* dinv   = (float*)alloc((size_t)N * 4);
    int*   rs     = (int*)alloc((size_t)N * 4);
    int*   re     = (int*)alloc((size_t)N * 4);
    int*   bcur   = (int*)alloc(NB2 * 4);
    int*   srcids = (int*)alloc((size_t)NB2 * sreg * 4);   // ~9.7 MB
    u16*   W1t    = (u16*)alloc((size_t)IN * HID * 2);     // [128][256] bf16
    u16*   W2t    = (u16*)alloc((size_t)HID * HID1 * 2);   // [64][128] bf16
    // shared region: bp2 (CSR build, 17MB) -> g1 (gemm1/agg128g2, 25.6MB); sequential.
    size_t bp2Bytes = (size_t)NB2 * bcap2 * 8;
    size_t gBytes = (size_t)(N + 1) * HID * 2;
    size_t sharedBytes = (gBytes > bp2Bytes) ? gBytes : bp2Bytes;
    char*  shared = (char*)alloc(sharedBytes);
    int2*  bp2    = (int2*)shared;
    u16*   g1     = (u16*)shared;                          // bf16 [N+1][128]
    u16*   g2     = (u16*)alloc((size_t)(N + 1) * HID1 * 2); // bf16 [N+1][64]

    // ---- init (weights cvt + bcur zero + sentinel rows) ----
    init_kernel<<<(IN * HID + HID * HID1 + 255) / 256, 256, 0, stream>>>(
        W1, W1t, IN, HID, W2, W2t, HID, HID1,
        bcur, (u32*)g1 + (size_t)N * 64, (u32*)g2 + (size_t)N * 32);

    // ---- CSR build: single-pass 256-way routing, padded rows ----
    const int nchunk = (E + CHUNK - 1) / CHUNK;            // 782
    route<<<nchunk, 256, 0, stream>>>(src, dst, E, R2, bcur, bp2, bcap2);
    build_csr<<<NB2, 256, 0, stream>>>(bp2, bcur, bcap2, sreg, R2, N, rs, re, dinv, srcids);

    const int gblocks = (N + 63) / 64;                     // 1563 (~6 blocks/CU)
    // layer 1 linear: g1 = bf16((x @ W1) * dinv)
    gemm_mfma<64, 256, 128, 2, 4, 2, 2, false><<<gblocks, 256, 0, stream>>>(x, W1t, dinv, g1, N);

    // fused: h1 = relu(agg(g1)*dinv + b1); g2 = bf16((h1 @ W2) * dinv)
    agg128g2<<<(N + 15) / 16, 256, 0, stream>>>((const uint4*)g1, (const float4*)b1,
                                                rs, re, srcids, dinv, W2t, g2, N);

    // fused: out = log_softmax((agg(g2)*dinv + b2) @ Wo + bo)
    agg64out<<<(N + 15) / 16, 256, 0, stream>>>((const uint2*)g2, (const float4*)b2,
                                                rs, re, srcids, dinv, Wo, bo, out, N);

    (void)ws_size; (void)n_in; (void)out_size; (void)HID1;
}